// Round 7
// baseline (291.430 us; speedup 1.0000x reference)
//
#include <hip/hip_runtime.h>
#include <cstdint>
#include <cstddef>

// Problem constants
#define NHEADS 16
#define HDIM   64
#define EMBED  1024
#define BATCH  2
#define SEQ    2048
#define BH     (BATCH*NHEADS)        // 32
#define MTOK   (BATCH*SEQ)           // 4096
#define NQKV   (3*NHEADS*HDIM)       // 3072

typedef _Float16 f16;
typedef __attribute__((ext_vector_type(4))) _Float16 f16x4;
typedef __attribute__((ext_vector_type(8))) _Float16 f16x8;
typedef __attribute__((ext_vector_type(4))) float f32x4;
typedef __attribute__((ext_vector_type(16))) float f32x16;

// pack two f32 -> one u32 of 2 f16 (RTZ)
__device__ __forceinline__ unsigned pkf16(float a, float b) {
    return __builtin_bit_cast(unsigned, __builtin_amdgcn_cvt_pkrtz(a, b));
}
// cross-32-lane max/add. shfl_xor-based: HW-proven in round 2/5/6.
__device__ __forceinline__ float cross32_max(float x) {
    return fmaxf(x, __shfl_xor(x, 32, 64));
}
__device__ __forceinline__ float cross32_add(float x) {
    return x + __shfl_xor(x, 32, 64);
}

// ---------------------------------------------------------------------------
// Transpose + fp32->f16 convert:  out[n][k] = (f16) in[k][n]
// ---------------------------------------------------------------------------
__global__ __launch_bounds__(256) void transpose_cvt_kernel(
    const float* __restrict__ in, f16* __restrict__ out, int K, int N)
{
    __shared__ float tile[32][33];
    const int n0 = blockIdx.x * 32;
    const int k0 = blockIdx.y * 32;
    const int tx = threadIdx.x & 31;
    const int ty = threadIdx.x >> 5;
#pragma unroll
    for (int j = 0; j < 4; ++j) {
        int k = ty + j * 8;
        tile[k][tx] = in[(size_t)(k0 + k) * N + n0 + tx];
    }
    __syncthreads();
#pragma unroll
    for (int j = 0; j < 4; ++j) {
        int n = ty + j * 8;
        out[(size_t)(n0 + n) * K + k0 + tx] = (f16)tile[tx][n];
    }
}

// ---------------------------------------------------------------------------
// GEMM1: QKV = X @ Wqkv + b  (M=4096, N=3072, K=1024)
// Epilogue: Q row-major (scaled 0.125*log2e), K and V in MFMA-FRAGMENT order
// so attention loads are base + lane*16B (fully coalesced):
//   Kf[bh][s/32][ds=d/16][lane = (d>>3&1)*32 + s%32][e = d%8]
//   Vf[bh][s/64][(d/32)*4 + (s%64)/16][lane = (s>>3&1)*32 + d%32][e = s%8]
// ---------------------------------------------------------------------------
__global__ __launch_bounds__(256, 2) void gemm_qkv_kernel(
    const float* __restrict__ X, const f16* __restrict__ WT,
    const float* __restrict__ bqkv,
    f16* __restrict__ Qb, f16* __restrict__ Kb, f16* __restrict__ Vt)
{
    __shared__ f16 As[128 * 32];
    __shared__ f16 Bs[128 * 32];
    const int tid = threadIdx.x;
    const int lane = tid & 63;
    const int wid = tid >> 6;
    const int wr = wid >> 1, wc = wid & 1;
    const int lhi = lane >> 4, llo = lane & 15;
    const int row0 = blockIdx.x * 128;
    const int col0 = blockIdx.y * 128;

    f32x4 acc[4][4] = {};

    for (int k0 = 0; k0 < EMBED; k0 += 32) {
        __syncthreads();
#pragma unroll
        for (int i = 0; i < 4; ++i) {
            int li = i * 256 + tid;
            int ar = li >> 3;
            int ac = (li & 7) * 4;
            float4 v = *reinterpret_cast<const float4*>(
                &X[(size_t)(row0 + ar) * EMBED + k0 + ac]);
            int byte = (ac * 2) ^ ((ar & 3) << 4);
            f16x4 h;
            h[0] = (f16)v.x; h[1] = (f16)v.y; h[2] = (f16)v.z; h[3] = (f16)v.w;
            *reinterpret_cast<f16x4*>((char*)As + ar * 64 + byte) = h;
        }
#pragma unroll
        for (int i = 0; i < 2; ++i) {
            int li = i * 256 + tid;
            int br = li >> 2;
            int bc = (li & 3) * 8;
            f16x8 v = *reinterpret_cast<const f16x8*>(
                &WT[(size_t)(col0 + br) * EMBED + k0 + bc]);
            int byte = (bc * 2) ^ ((br & 3) << 4);
            *reinterpret_cast<f16x8*>((char*)Bs + br * 64 + byte) = v;
        }
        __syncthreads();
        f16x8 af[4], bf[4];
#pragma unroll
        for (int m = 0; m < 4; ++m) {
            int ar = wr * 64 + m * 16 + llo;
            int byte = (lhi * 16) ^ ((ar & 3) << 4);
            af[m] = *reinterpret_cast<const f16x8*>((const char*)As + ar * 64 + byte);
        }
#pragma unroll
        for (int n = 0; n < 4; ++n) {
            int br = wc * 64 + n * 16 + llo;
            int byte = (lhi * 16) ^ ((br & 3) << 4);
            bf[n] = *reinterpret_cast<const f16x8*>((const char*)Bs + br * 64 + byte);
        }
#pragma unroll
        for (int m = 0; m < 4; ++m)
#pragma unroll
            for (int n = 0; n < 4; ++n)
                acc[m][n] = __builtin_amdgcn_mfma_f32_16x16x32_f16(
                    af[m], bf[n], acc[m][n], 0, 0, 0);
    }

#pragma unroll
    for (int m = 0; m < 4; ++m) {
#pragma unroll
        for (int n = 0; n < 4; ++n) {
#pragma unroll
            for (int r = 0; r < 4; ++r) {
                int mg = row0 + wr * 64 + m * 16 + lhi * 4 + r;
                int ng = col0 + wc * 64 + n * 16 + llo;
                float v = acc[m][n][r] + bqkv[ng];
                int t = ng >> 10;
                int h = (ng >> 6) & 15;
                int d = ng & 63;
                int b = mg >> 11;
                int s = mg & (SEQ - 1);
                int bh = b * NHEADS + h;
                if (t == 0) {
                    Qb[((size_t)bh * SEQ + s) * HDIM + d] = (f16)(v * 0.18033688011f);
                } else if (t == 1) {
                    size_t off = ((size_t)(bh * (SEQ >> 5) + (s >> 5)) * 4 + (d >> 4)) * 512
                               + (size_t)((((d >> 3) & 1) << 5) + (s & 31)) * 8 + (d & 7);
                    Kb[off] = (f16)v;
                } else {
                    size_t off = ((size_t)(bh * (SEQ >> 6) + (s >> 6)) * 8
                                  + (d >> 5) * 4 + ((s >> 4) & 3)) * 512
                               + (size_t)((((s >> 3) & 1) << 5) + (d & 31)) * 8 + (s & 7);
                    Vt[off] = (f16)v;
                }
            }
        }
    }
}

// ---------------------------------------------------------------------------
// Flash attention: swapped-operand in-register softmax, fragment-layout K/V,
// in-block KV-split for occupancy. Grid (BH, SEQ/128); 8 waves/block:
// waves 0-3 do KV[0:1024], waves 4-7 do KV[1024:2048] for the same 4 q-tiles
// (32 q-rows each). Flash-combine via LDS at the end (per-lane merge: both
// waves share the exact (q,d,hi) register mapping). 16 waves/CU = 4/SIMD.
// ---------------------------------------------------------------------------
#define LOADK(KF, KB) do {                                                     \
    const f16* kbase_ = Kp + ((size_t)((KB) >> 5) * 4) * 512;                  \
    _Pragma("unroll")                                                          \
    for (int j_ = 0; j_ < 2; ++j_)                                             \
        _Pragma("unroll")                                                      \
        for (int ds_ = 0; ds_ < 4; ++ds_)                                      \
            KF[j_*4+ds_] = *reinterpret_cast<const f16x8*>(                    \
                kbase_ + (size_t)(j_*4 + ds_) * 512 + lane * 8);               \
} while (0)

#define LOADV(VF, KB) do {                                                     \
    const f16* vbase_ = Vp + ((size_t)((KB) >> 6) * 8) * 512;                  \
    _Pragma("unroll")                                                          \
    for (int i_ = 0; i_ < 8; ++i_)                                             \
        VF[i_] = *reinterpret_cast<const f16x8*>(                              \
            vbase_ + (size_t)i_ * 512 + lane * 8);                             \
} while (0)

#define STEP(KF, VF) do {                                                      \
    f32x16 st0 = {}, st1 = {};                                                 \
    __builtin_amdgcn_s_setprio(1);                                             \
    _Pragma("unroll")                                                          \
    for (int ds_ = 0; ds_ < 4; ++ds_) {                                        \
        st0 = __builtin_amdgcn_mfma_f32_32x32x16_f16(KF[ds_],   qf[ds_], st0, 0, 0, 0); \
        st1 = __builtin_amdgcn_mfma_f32_32x32x16_f16(KF[4+ds_], qf[ds_], st1, 0, 0, 0); \
    }                                                                          \
    __builtin_amdgcn_s_setprio(0);                                             \
    float red[16];                                                             \
    _Pragma("unroll")                                                          \
    for (int r_ = 0; r_ < 16; ++r_) red[r_] = fmaxf(st0[r_], st1[r_]);         \
    _Pragma("unroll")                                                          \
    for (int w_ = 8; w_ >= 1; w_ >>= 1)                                        \
        _Pragma("unroll")                                                      \
        for (int r_ = 0; r_ < w_; ++r_) red[r_] = fmaxf(red[r_], red[r_+w_]);  \
    float pm = cross32_max(red[0]);                                            \
    if (!__all(pm - m <= 8.0f)) {                                              \
        float mn = fmaxf(m, pm);                                               \
        float sc = __builtin_amdgcn_exp2f(m - mn);                             \
        m = mn; l *= sc;                                                       \
        _Pragma("unroll")                                                      \
        for (int r_ = 0; r_ < 16; ++r_) { o[0][r_] *= sc; o[1][r_] *= sc; }    \
    }                                                                          \
    _Pragma("unroll")                                                          \
    for (int r_ = 0; r_ < 16; ++r_) {                                          \
        st0[r_] = __builtin_amdgcn_exp2f(st0[r_] - m);                         \
        st1[r_] = __builtin_amdgcn_exp2f(st1[r_] - m);                         \
    }                                                                          \
    _Pragma("unroll")                                                          \
    for (int r_ = 0; r_ < 16; ++r_) red[r_] = st0[r_] + st1[r_];               \
    _Pragma("unroll")                                                          \
    for (int w_ = 8; w_ >= 1; w_ >>= 1)                                        \
        _Pragma("unroll")                                                      \
        for (int r_ = 0; r_ < w_; ++r_) red[r_] += red[r_+w_];                 \
    l += red[0];                                                               \
    f16x8 pf[4];                                                               \
    {                                                                          \
        unsigned a0 = pkf16(st0[0],  st0[1]),  a1 = pkf16(st0[2],  st0[3]);    \
        unsigned b0 = pkf16(st0[4],  st0[5]),  b1 = pkf16(st0[6],  st0[7]);    \
        unsigned c0 = pkf16(st0[8],  st0[9]),  c1 = pkf16(st0[10], st0[11]);   \
        unsigned d0 = pkf16(st0[12], st0[13]), d1 = pkf16(st0[14], st0[15]);   \
        asm("v_permlane32_swap_b32 %0, %1" : "+v"(a0), "+v"(b0));              \
        asm("v_permlane32_swap_b32 %0, %1" : "+v"(a1), "+v"(b1));              \
        asm("v_permlane32_swap_b32 %0, %1" : "+v"(c0), "+v"(d0));              \
        asm("v_permlane32_swap_b32 %0, %1" : "+v"(c1), "+v"(d1));              \
        uint4 w0; w0.x = a0; w0.y = a1; w0.z = b0; w0.w = b1;                  \
        uint4 w1; w1.x = c0; w1.y = c1; w1.z = d0; w1.w = d1;                  \
        pf[0] = __builtin_bit_cast(f16x8, w0);                                 \
        pf[1] = __builtin_bit_cast(f16x8, w1);                                 \
    }                                                                          \
    {                                                                          \
        unsigned a0 = pkf16(st1[0],  st1[1]),  a1 = pkf16(st1[2],  st1[3]);    \
        unsigned b0 = pkf16(st1[4],  st1[5]),  b1 = pkf16(st1[6],  st1[7]);    \
        unsigned c0 = pkf16(st1[8],  st1[9]),  c1 = pkf16(st1[10], st1[11]);   \
        unsigned d0 = pkf16(st1[12], st1[13]), d1 = pkf16(st1[14], st1[15]);   \
        asm("v_permlane32_swap_b32 %0, %1" : "+v"(a0), "+v"(b0));              \
        asm("v_permlane32_swap_b32 %0, %1" : "+v"(a1), "+v"(b1));              \
        asm("v_permlane32_swap_b32 %0, %1" : "+v"(c0), "+v"(d0));              \
        asm("v_permlane32_swap_b32 %0, %1" : "+v"(c1), "+v"(d1));              \
        uint4 w0; w0.x = a0; w0.y = a1; w0.z = b0; w0.w = b1;                  \
        uint4 w1; w1.x = c0; w1.y = c1; w1.z = d0; w1.w = d1;                  \
        pf[2] = __builtin_bit_cast(f16x8, w0);                                 \
        pf[3] = __builtin_bit_cast(f16x8, w1);                                 \
    }                                                                          \
    __builtin_amdgcn_s_setprio(1);                                             \
    _Pragma("unroll")                                                          \
    for (int dt_ = 0; dt_ < 2; ++dt_)                                          \
        _Pragma("unroll")                                                      \
        for (int f_ = 0; f_ < 4; ++f_)                                         \
            o[dt_] = __builtin_amdgcn_mfma_f32_32x32x16_f16(                   \
                VF[dt_*4+f_], pf[f_], o[dt_], 0, 0, 0);                        \
    __builtin_amdgcn_s_setprio(0);                                             \
} while (0)

__global__ __launch_bounds__(512, 4) void attn_kernel(
    const f16* __restrict__ Qb, const f16* __restrict__ Kb,
    const f16* __restrict__ Vt, f16* __restrict__ ctx)
{
    __shared__ float Xo[4][64][34];   // partial-O exchange (padded: 4-way max)
    __shared__ float Xml[4][64][2];   // partial m,l
    __shared__ f16 Ol[4][32 * 64];    // 16KB: output transpose patch (waves 0-3)
    const int tid = threadIdx.x;
    const int lane = tid & 63;
    const int wid = tid >> 6;         // 0..7
    const int pair = wid & 3;
    const int half = wid >> 2;        // 0: KV[0:1024], 1: KV[1024:2048]
    const int q = lane & 31;
    const int hi = lane >> 5;
    const int bh = blockIdx.x;
    const int q0 = blockIdx.y * 128 + pair * 32;
    const int kb0 = half << 10;
    const f16* Qp = Qb + (size_t)bh * SEQ * HDIM;
    const f16* Kp = Kb + (size_t)bh * SEQ * HDIM;
    const f16* Vp = Vt + (size_t)bh * SEQ * HDIM;

    f16x8 qf[4];
#pragma unroll
    for (int ds = 0; ds < 4; ++ds)
        qf[ds] = *reinterpret_cast<const f16x8*>(
            Qp + (size_t)(q0 + q) * HDIM + ds * 16 + hi * 8);

    f32x16 o[2] = {};
    float m = -1e30f, l = 0.f;

    f16x8 ka[8], kn[8], va[8];
    LOADK(ka, kb0);
    for (int kb = kb0; kb < kb0 + 1024; kb += 128) {
        LOADV(va, kb);
        LOADK(kn, kb + 64);
        STEP(ka, va);
        LOADV(va, kb + 64);
        LOADK(ka, (kb + 128) & (SEQ - 1));
        STEP(kn, va);
    }

    // ---- flash-combine across the two KV halves (per-lane: same (q,d,hi)
    // register mapping in both waves of a pair)
    if (wid >= 4) {
#pragma unroll
        for (int dt = 0; dt < 2; ++dt)
#pragma unroll
            for (int r = 0; r < 16; ++r)
                Xo[pair][lane][dt * 16 + r] = o[dt][r];
        Xml[pair][lane][0] = m;
        Xml[pair][lane][1] = l;
    }
    __syncthreads();
    if (wid < 4) {
        float mb = Xml[pair][lane][0];
        float lb = Xml[pair][lane][1];
        float mm = fmaxf(m, mb);
        float sa = __builtin_amdgcn_exp2f(m - mm);
        float sb = __builtin_amdgcn_exp2f(mb - mm);
        l = l * sa + lb * sb;
#pragma unroll
        for (int dt = 0; dt < 2; ++dt)
#pragma unroll
            for (int r = 0; r < 16; ++r)
                o[dt][r] = o[dt][r] * sa + Xo[pair][lane][dt * 16 + r] * sb;

        // ---- epilogue: normalize, transpose via swizzled LDS, coalesced store
        float lt = cross32_add(l);
        float inv = __builtin_amdgcn_rcpf(lt);
        char* base = (char*)&Ol[pair][0];
#pragma unroll
        for (int dt = 0; dt < 2; ++dt)
#pragma unroll
            for (int rp = 0; rp < 8; ++rp) {
                int r = rp * 2;
                int d = dt * 32 + (r & 3) + 8 * (r >> 2) + 4 * hi;
                unsigned w = pkf16(o[dt][r] * inv, o[dt][r + 1] * inv);
                int byte = (q * 128 + d * 2) ^ ((q & 7) << 4);
                *reinterpret_cast<unsigned*>(base + byte) = w;
            }
    }
    __syncthreads();
    if (wid < 4) {
        int row = lane >> 1, half2 = lane & 1;
        const char* rb = (const char*)&Ol[pair][0] + row * 128;
        int b = bh >> 4, h = bh & 15;
        f16* orow = ctx + (size_t)(b * SEQ + q0 + row) * EMBED + h * HDIM;
#pragma unroll
        for (int i = 0; i < 4; ++i) {
            int c = half2 * 64 + i * 16;
            int4 v = *reinterpret_cast<const int4*>(rb + (c ^ ((row & 7) << 4)));
            *reinterpret_cast<int4*>((char*)orow + c) = v;
        }
    }
}

// ---------------------------------------------------------------------------
// GEMM2: out = ctx @ Wo + bo  (M=4096, N=1024, K=1024), fp32 output.
// ---------------------------------------------------------------------------
__global__ __launch_bounds__(256, 2) void gemm_out_kernel(
    const f16* __restrict__ A, const f16* __restrict__ WT,
    const float* __restrict__ bo, float* __restrict__ out)
{
    __shared__ f16 As[128 * 32];
    __shared__ f16 Bs[128 * 32];
    const int tid = threadIdx.x;
    const int lane = tid & 63;
    const int wid = tid >> 6;
    const int wr = wid >> 1, wc = wid & 1;
    const int lhi = lane >> 4, llo = lane & 15;
    const int row0 = blockIdx.x * 128;
    const int col0 = blockIdx.y * 128;

    f32x4 acc[4][4] = {};

    for (int k0 = 0; k0 < EMBED; k0 += 32) {
        __syncthreads();
#pragma unroll
        for (int i = 0; i < 2; ++i) {
            int li = i * 256 + tid;
            int ar = li >> 2;
            int ac = (li & 3) * 8;
            f16x8 v = *reinterpret_cast<const f16x8*>(
                &A[(size_t)(row0 + ar) * EMBED + k0 + ac]);
            int byte = (ac * 2) ^ ((ar & 3) << 4);
            *reinterpret_cast<f16x8*>((char*)As + ar * 64 + byte) = v;
        }
#pragma unroll
        for (int i = 0; i < 2; ++i) {
            int li = i * 256 + tid;
            int br = li >> 2;
            int bc = (li & 3) * 8;
            f16x8 v = *reinterpret_cast<const f16x8*>(
                &WT[(size_t)(col0 + br) * EMBED + k0 + bc]);
            int byte = (bc * 2) ^ ((br & 3) << 4);
            *reinterpret_cast<f16x8*>((char*)Bs + br * 64 + byte) = v;
        }
        __syncthreads();
        f16x8 af[4], bf[4];
#pragma unroll
        for (int m = 0; m < 4; ++m) {
            int ar = wr * 64 + m * 16 + llo;
            int byte = (lhi * 16) ^ ((ar & 3) << 4);
            af[m] = *reinterpret_cast<const f16x8*>((const char*)As + ar * 64 + byte);
        }
#pragma unroll
        for (int n = 0; n < 4; ++n) {
            int br = wc * 64 + n * 16 + llo;
            int byte = (lhi * 16) ^ ((br & 3) << 4);
            bf[n] = *reinterpret_cast<const f16x8*>((const char*)Bs + br * 64 + byte);
        }
#pragma unroll
        for (int m = 0; m < 4; ++m)
#pragma unroll
            for (int n = 0; n < 4; ++n)
                acc[m][n] = __builtin_amdgcn_mfma_f32_16x16x32_f16(
                    af[m], bf[n], acc[m][n], 0, 0, 0);
    }

#pragma unroll
    for (int m = 0; m < 4; ++m)
#pragma unroll
        for (int n = 0; n < 4; ++n)
#pragma unroll
            for (int r = 0; r < 4; ++r) {
                int mg = row0 + wr * 64 + m * 16 + lhi * 4 + r;
                int ng = col0 + wc * 64 + n * 16 + llo;
                out[(size_t)mg * EMBED + ng] = acc[m][n][r] + bo[ng];
            }
}

// ---------------------------------------------------------------------------
extern "C" void kernel_launch(void* const* d_in, const int* in_sizes, int n_in,
                              void* d_out, int out_size, void* d_ws, size_t ws_size,
                              hipStream_t stream)
{
    const float* x     = (const float*)d_in[0];
    const float* w_qkv = (const float*)d_in[1];
    const float* b_qkv = (const float*)d_in[2];
    const float* w_o   = (const float*)d_in[3];
    const float* b_o   = (const float*)d_in[4];
    float* out = (float*)d_out;

    char* ws = (char*)d_ws;
    f16* wqkvT = (f16*)ws; ws += (size_t)NQKV * EMBED * 2;
    f16* woT   = (f16*)ws; ws += (size_t)EMBED * EMBED * 2;
    f16* Qb    = (f16*)ws; ws += (size_t)BH * SEQ * HDIM * 2;
    f16* Kb    = (f16*)ws; ws += (size_t)BH * SEQ * HDIM * 2;
    f16* Vt    = (f16*)ws; ws += (size_t)BH * SEQ * HDIM * 2;
    f16* ctx   = (f16*)ws; ws += (size_t)MTOK * EMBED * 2;

    hipLaunchKernelGGL(transpose_cvt_kernel, dim3(NQKV / 32, EMBED / 32), dim3(256),
                       0, stream, w_qkv, wqkvT, EMBED, NQKV);
    hipLaunchKernelGGL(transpose_cvt_kernel, dim3(EMBED / 32, EMBED / 32), dim3(256),
                       0, stream, w_o, woT, EMBED, EMBED);
    hipLaunchKernelGGL(gemm_qkv_kernel, dim3(MTOK / 128, NQKV / 128), dim3(256),
                       0, stream, x, wqkvT, b_qkv, Qb, Kb, Vt);
    hipLaunchKernelGGL(attn_kernel, dim3(BH, SEQ / 128), dim3(512),
                       0, stream, Qb, Kb, Vt, ctx);
    hipLaunchKernelGGL(gemm_out_kernel, dim3(MTOK / 128, EMBED / 128), dim3(256),
                       0, stream, ctx, woT, b_o, out);
}

// Round 8
// 134.641 us; speedup vs baseline: 2.1645x; 2.1645x over previous
//
#include <hip/hip_runtime.h>
#include <cstdint>
#include <cstddef>

// Problem constants
#define NHEADS 16
#define HDIM   64
#define EMBED  1024
#define BATCH  2
#define SEQ    2048
#define BH     (BATCH*NHEADS)        // 32
#define MTOK   (BATCH*SEQ)           // 4096
#define NQKV   (3*NHEADS*HDIM)       // 3072

typedef _Float16 f16;
typedef __attribute__((ext_vector_type(4))) _Float16 f16x4;
typedef __attribute__((ext_vector_type(8))) _Float16 f16x8;
typedef __attribute__((ext_vector_type(4))) float f32x4;
typedef __attribute__((ext_vector_type(16))) float f32x16;

// pack two f32 -> one u32 of 2 f16 (RTZ)
__device__ __forceinline__ unsigned pkf16(float a, float b) {
    return __builtin_bit_cast(unsigned, __builtin_amdgcn_cvt_pkrtz(a, b));
}
// cross-32-lane max/add. shfl_xor-based: HW-proven in round 2/5/6.
__device__ __forceinline__ float cross32_max(float x) {
    return fmaxf(x, __shfl_xor(x, 32, 64));
}
__device__ __forceinline__ float cross32_add(float x) {
    return x + __shfl_xor(x, 32, 64);
}

// ---------------------------------------------------------------------------
// Transpose + fp32->f16 convert:  out[n][k] = (f16) in[k][n]
// ---------------------------------------------------------------------------
__global__ __launch_bounds__(256) void transpose_cvt_kernel(
    const float* __restrict__ in, f16* __restrict__ out, int K, int N)
{
    __shared__ float tile[32][33];
    const int n0 = blockIdx.x * 32;
    const int k0 = blockIdx.y * 32;
    const int tx = threadIdx.x & 31;
    const int ty = threadIdx.x >> 5;
#pragma unroll
    for (int j = 0; j < 4; ++j) {
        int k = ty + j * 8;
        tile[k][tx] = in[(size_t)(k0 + k) * N + n0 + tx];
    }
    __syncthreads();
#pragma unroll
    for (int j = 0; j < 4; ++j) {
        int n = ty + j * 8;
        out[(size_t)(n0 + n) * K + k0 + tx] = (f16)tile[tx][n];
    }
}

// ---------------------------------------------------------------------------
// GEMM1: QKV = X @ Wqkv + b  (M=4096, N=3072, K=1024)
// Epilogue: Q row-major (scaled 0.125*log2e), K and V in MFMA-FRAGMENT order
// so attention loads are base + lane*16B (fully coalesced):
//   Kf[bh][s/32][ds=d/16][lane = (d>>3&1)*32 + s%32][e = d%8]
//   Vf[bh][s/64][(d/32)*4 + (s%64)/16][lane = (s>>3&1)*32 + d%32][e = s%8]
// ---------------------------------------------------------------------------
__global__ __launch_bounds__(256, 2) void gemm_qkv_kernel(
    const float* __restrict__ X, const f16* __restrict__ WT,
    const float* __restrict__ bqkv,
    f16* __restrict__ Qb, f16* __restrict__ Kb, f16* __restrict__ Vt)
{
    __shared__ f16 As[128 * 32];
    __shared__ f16 Bs[128 * 32];
    const int tid = threadIdx.x;
    const int lane = tid & 63;
    const int wid = tid >> 6;
    const int wr = wid >> 1, wc = wid & 1;
    const int lhi = lane >> 4, llo = lane & 15;
    const int row0 = blockIdx.x * 128;
    const int col0 = blockIdx.y * 128;

    f32x4 acc[4][4] = {};

    for (int k0 = 0; k0 < EMBED; k0 += 32) {
        __syncthreads();
#pragma unroll
        for (int i = 0; i < 4; ++i) {
            int li = i * 256 + tid;
            int ar = li >> 3;
            int ac = (li & 7) * 4;
            float4 v = *reinterpret_cast<const float4*>(
                &X[(size_t)(row0 + ar) * EMBED + k0 + ac]);
            int byte = (ac * 2) ^ ((ar & 3) << 4);
            f16x4 h;
            h[0] = (f16)v.x; h[1] = (f16)v.y; h[2] = (f16)v.z; h[3] = (f16)v.w;
            *reinterpret_cast<f16x4*>((char*)As + ar * 64 + byte) = h;
        }
#pragma unroll
        for (int i = 0; i < 2; ++i) {
            int li = i * 256 + tid;
            int br = li >> 2;
            int bc = (li & 3) * 8;
            f16x8 v = *reinterpret_cast<const f16x8*>(
                &WT[(size_t)(col0 + br) * EMBED + k0 + bc]);
            int byte = (bc * 2) ^ ((br & 3) << 4);
            *reinterpret_cast<f16x8*>((char*)Bs + br * 64 + byte) = v;
        }
        __syncthreads();
        f16x8 af[4], bf[4];
#pragma unroll
        for (int m = 0; m < 4; ++m) {
            int ar = wr * 64 + m * 16 + llo;
            int byte = (lhi * 16) ^ ((ar & 3) << 4);
            af[m] = *reinterpret_cast<const f16x8*>((const char*)As + ar * 64 + byte);
        }
#pragma unroll
        for (int n = 0; n < 4; ++n) {
            int br = wc * 64 + n * 16 + llo;
            int byte = (lhi * 16) ^ ((br & 3) << 4);
            bf[n] = *reinterpret_cast<const f16x8*>((const char*)Bs + br * 64 + byte);
        }
#pragma unroll
        for (int m = 0; m < 4; ++m)
#pragma unroll
            for (int n = 0; n < 4; ++n)
                acc[m][n] = __builtin_amdgcn_mfma_f32_16x16x32_f16(
                    af[m], bf[n], acc[m][n], 0, 0, 0);
    }

#pragma unroll
    for (int m = 0; m < 4; ++m) {
#pragma unroll
        for (int n = 0; n < 4; ++n) {
#pragma unroll
            for (int r = 0; r < 4; ++r) {
                int mg = row0 + wr * 64 + m * 16 + lhi * 4 + r;
                int ng = col0 + wc * 64 + n * 16 + llo;
                float v = acc[m][n][r] + bqkv[ng];
                int t = ng >> 10;
                int h = (ng >> 6) & 15;
                int d = ng & 63;
                int b = mg >> 11;
                int s = mg & (SEQ - 1);
                int bh = b * NHEADS + h;
                if (t == 0) {
                    Qb[((size_t)bh * SEQ + s) * HDIM + d] = (f16)(v * 0.18033688011f);
                } else if (t == 1) {
                    size_t off = ((size_t)(bh * (SEQ >> 5) + (s >> 5)) * 4 + (d >> 4)) * 512
                               + (size_t)((((d >> 3) & 1) << 5) + (s & 31)) * 8 + (d & 7);
                    Kb[off] = (f16)v;
                } else {
                    size_t off = ((size_t)(bh * (SEQ >> 6) + (s >> 6)) * 8
                                  + (d >> 5) * 4 + ((s >> 4) & 3)) * 512
                               + (size_t)((((s >> 3) & 1) << 5) + (d & 31)) * 8 + (s & 7);
                    Vt[off] = (f16)v;
                }
            }
        }
    }
}

// ---------------------------------------------------------------------------
// Flash attention: swapped-operand in-register softmax, fragment-layout K/V,
// in-block KV-split for occupancy. Grid (BH, SEQ/128); 8 waves/block:
// waves 0-3 do KV[0:1024], waves 4-7 do KV[1024:2048] for the same 4 q-tiles
// (32 q-rows each). Flash-combine via LDS at the end.
// __launch_bounds__ 2nd arg is CUDA-style min BLOCKS/CU (round-7 lesson:
// (512,4) capped VGPR at 64 -> catastrophic spill). (512,2) = 16 waves/CU
// = 4 waves/SIMD, VGPR cap 128.
// ---------------------------------------------------------------------------
#define LOADK(KF, KB) do {                                                     \
    const f16* kbase_ = Kp + ((size_t)((KB) >> 5) * 4) * 512;                  \
    _Pragma("unroll")                                                          \
    for (int j_ = 0; j_ < 2; ++j_)                                             \
        _Pragma("unroll")                                                      \
        for (int ds_ = 0; ds_ < 4; ++ds_)                                      \
            KF[j_*4+ds_] = *reinterpret_cast<const f16x8*>(                    \
                kbase_ + (size_t)(j_*4 + ds_) * 512 + lane * 8);               \
} while (0)

#define LOADV(VF, KB) do {                                                     \
    const f16* vbase_ = Vp + ((size_t)((KB) >> 6) * 8) * 512;                  \
    _Pragma("unroll")                                                          \
    for (int i_ = 0; i_ < 8; ++i_)                                             \
        VF[i_] = *reinterpret_cast<const f16x8*>(                              \
            vbase_ + (size_t)i_ * 512 + lane * 8);                             \
} while (0)

#define STEP(KF, VF) do {                                                      \
    f32x16 st0 = {}, st1 = {};                                                 \
    __builtin_amdgcn_s_setprio(1);                                             \
    _Pragma("unroll")                                                          \
    for (int ds_ = 0; ds_ < 4; ++ds_) {                                        \
        st0 = __builtin_amdgcn_mfma_f32_32x32x16_f16(KF[ds_],   qf[ds_], st0, 0, 0, 0); \
        st1 = __builtin_amdgcn_mfma_f32_32x32x16_f16(KF[4+ds_], qf[ds_], st1, 0, 0, 0); \
    }                                                                          \
    __builtin_amdgcn_s_setprio(0);                                             \
    float red[16];                                                             \
    _Pragma("unroll")                                                          \
    for (int r_ = 0; r_ < 16; ++r_) red[r_] = fmaxf(st0[r_], st1[r_]);         \
    _Pragma("unroll")                                                          \
    for (int w_ = 8; w_ >= 1; w_ >>= 1)                                        \
        _Pragma("unroll")                                                      \
        for (int r_ = 0; r_ < w_; ++r_) red[r_] = fmaxf(red[r_], red[r_+w_]);  \
    float pm = cross32_max(red[0]);                                            \
    if (!__all(pm - m <= 8.0f)) {                                              \
        float mn = fmaxf(m, pm);                                               \
        float sc = __builtin_amdgcn_exp2f(m - mn);                             \
        m = mn; l *= sc;                                                       \
        _Pragma("unroll")                                                      \
        for (int r_ = 0; r_ < 16; ++r_) { o[0][r_] *= sc; o[1][r_] *= sc; }    \
    }                                                                          \
    _Pragma("unroll")                                                          \
    for (int r_ = 0; r_ < 16; ++r_) {                                          \
        st0[r_] = __builtin_amdgcn_exp2f(st0[r_] - m);                         \
        st1[r_] = __builtin_amdgcn_exp2f(st1[r_] - m);                         \
    }                                                                          \
    _Pragma("unroll")                                                          \
    for (int r_ = 0; r_ < 16; ++r_) red[r_] = st0[r_] + st1[r_];               \
    _Pragma("unroll")                                                          \
    for (int w_ = 8; w_ >= 1; w_ >>= 1)                                        \
        _Pragma("unroll")                                                      \
        for (int r_ = 0; r_ < w_; ++r_) red[r_] += red[r_+w_];                 \
    l += red[0];                                                               \
    f16x8 pf[4];                                                               \
    {                                                                          \
        unsigned a0 = pkf16(st0[0],  st0[1]),  a1 = pkf16(st0[2],  st0[3]);    \
        unsigned b0 = pkf16(st0[4],  st0[5]),  b1 = pkf16(st0[6],  st0[7]);    \
        unsigned c0 = pkf16(st0[8],  st0[9]),  c1 = pkf16(st0[10], st0[11]);   \
        unsigned d0 = pkf16(st0[12], st0[13]), d1 = pkf16(st0[14], st0[15]);   \
        asm("v_permlane32_swap_b32 %0, %1" : "+v"(a0), "+v"(b0));              \
        asm("v_permlane32_swap_b32 %0, %1" : "+v"(a1), "+v"(b1));              \
        asm("v_permlane32_swap_b32 %0, %1" : "+v"(c0), "+v"(d0));              \
        asm("v_permlane32_swap_b32 %0, %1" : "+v"(c1), "+v"(d1));              \
        uint4 w0; w0.x = a0; w0.y = a1; w0.z = b0; w0.w = b1;                  \
        uint4 w1; w1.x = c0; w1.y = c1; w1.z = d0; w1.w = d1;                  \
        pf[0] = __builtin_bit_cast(f16x8, w0);                                 \
        pf[1] = __builtin_bit_cast(f16x8, w1);                                 \
    }                                                                          \
    {                                                                          \
        unsigned a0 = pkf16(st1[0],  st1[1]),  a1 = pkf16(st1[2],  st1[3]);    \
        unsigned b0 = pkf16(st1[4],  st1[5]),  b1 = pkf16(st1[6],  st1[7]);    \
        unsigned c0 = pkf16(st1[8],  st1[9]),  c1 = pkf16(st1[10], st1[11]);   \
        unsigned d0 = pkf16(st1[12], st1[13]), d1 = pkf16(st1[14], st1[15]);   \
        asm("v_permlane32_swap_b32 %0, %1" : "+v"(a0), "+v"(b0));              \
        asm("v_permlane32_swap_b32 %0, %1" : "+v"(a1), "+v"(b1));              \
        asm("v_permlane32_swap_b32 %0, %1" : "+v"(c0), "+v"(d0));              \
        asm("v_permlane32_swap_b32 %0, %1" : "+v"(c1), "+v"(d1));              \
        uint4 w0; w0.x = a0; w0.y = a1; w0.z = b0; w0.w = b1;                  \
        uint4 w1; w1.x = c0; w1.y = c1; w1.z = d0; w1.w = d1;                  \
        pf[2] = __builtin_bit_cast(f16x8, w0);                                 \
        pf[3] = __builtin_bit_cast(f16x8, w1);                                 \
    }                                                                          \
    __builtin_amdgcn_s_setprio(1);                                             \
    _Pragma("unroll")                                                          \
    for (int dt_ = 0; dt_ < 2; ++dt_)                                          \
        _Pragma("unroll")                                                      \
        for (int f_ = 0; f_ < 4; ++f_)                                         \
            o[dt_] = __builtin_amdgcn_mfma_f32_32x32x16_f16(                   \
                VF[dt_*4+f_], pf[f_], o[dt_], 0, 0, 0);                        \
    __builtin_amdgcn_s_setprio(0);                                             \
} while (0)

__global__ __launch_bounds__(512, 2) void attn_kernel(
    const f16* __restrict__ Qb, const f16* __restrict__ Kb,
    const f16* __restrict__ Vt, f16* __restrict__ ctx)
{
    __shared__ float Xo[4][64][34];   // partial-O exchange (padded: 4-way max)
    __shared__ float Xml[4][64][2];   // partial m,l
    __shared__ f16 Ol[4][32 * 64];    // 16KB: output transpose patch (waves 0-3)
    const int tid = threadIdx.x;
    const int lane = tid & 63;
    const int wid = tid >> 6;         // 0..7
    const int pair = wid & 3;
    const int half = wid >> 2;        // 0: KV[0:1024], 1: KV[1024:2048]
    const int q = lane & 31;
    const int hi = lane >> 5;
    const int bh = blockIdx.x;
    const int q0 = blockIdx.y * 128 + pair * 32;
    const int kb0 = half << 10;
    const f16* Qp = Qb + (size_t)bh * SEQ * HDIM;
    const f16* Kp = Kb + (size_t)bh * SEQ * HDIM;
    const f16* Vp = Vt + (size_t)bh * SEQ * HDIM;

    f16x8 qf[4];
#pragma unroll
    for (int ds = 0; ds < 4; ++ds)
        qf[ds] = *reinterpret_cast<const f16x8*>(
            Qp + (size_t)(q0 + q) * HDIM + ds * 16 + hi * 8);

    f32x16 o[2] = {};
    float m = -1e30f, l = 0.f;

    f16x8 ka[8], kn[8], va[8];
    LOADK(ka, kb0);
    for (int kb = kb0; kb < kb0 + 1024; kb += 128) {
        LOADV(va, kb);
        LOADK(kn, kb + 64);
        STEP(ka, va);
        LOADV(va, kb + 64);
        LOADK(ka, (kb + 128) & (SEQ - 1));
        STEP(kn, va);
    }

    // ---- flash-combine across the two KV halves (per-lane: same (q,d,hi)
    // register mapping in both waves of a pair)
    if (wid >= 4) {
#pragma unroll
        for (int dt = 0; dt < 2; ++dt)
#pragma unroll
            for (int r = 0; r < 16; ++r)
                Xo[pair][lane][dt * 16 + r] = o[dt][r];
        Xml[pair][lane][0] = m;
        Xml[pair][lane][1] = l;
    }
    __syncthreads();
    if (wid < 4) {
        float mb = Xml[pair][lane][0];
        float lb = Xml[pair][lane][1];
        float mm = fmaxf(m, mb);
        float sa = __builtin_amdgcn_exp2f(m - mm);
        float sb = __builtin_amdgcn_exp2f(mb - mm);
        l = l * sa + lb * sb;
#pragma unroll
        for (int dt = 0; dt < 2; ++dt)
#pragma unroll
            for (int r = 0; r < 16; ++r)
                o[dt][r] = o[dt][r] * sa + Xo[pair][lane][dt * 16 + r] * sb;

        // ---- epilogue: normalize, transpose via swizzled LDS, coalesced store
        float lt = cross32_add(l);
        float inv = __builtin_amdgcn_rcpf(lt);
        char* base = (char*)&Ol[pair][0];
#pragma unroll
        for (int dt = 0; dt < 2; ++dt)
#pragma unroll
            for (int rp = 0; rp < 8; ++rp) {
                int r = rp * 2;
                int d = dt * 32 + (r & 3) + 8 * (r >> 2) + 4 * hi;
                unsigned w = pkf16(o[dt][r] * inv, o[dt][r + 1] * inv);
                int byte = (q * 128 + d * 2) ^ ((q & 7) << 4);
                *reinterpret_cast<unsigned*>(base + byte) = w;
            }
    }
    __syncthreads();
    if (wid < 4) {
        int row = lane >> 1, half2 = lane & 1;
        const char* rb = (const char*)&Ol[pair][0] + row * 128;
        int b = bh >> 4, h = bh & 15;
        f16* orow = ctx + (size_t)(b * SEQ + q0 + row) * EMBED + h * HDIM;
#pragma unroll
        for (int i = 0; i < 4; ++i) {
            int c = half2 * 64 + i * 16;
            int4 v = *reinterpret_cast<const int4*>(rb + (c ^ ((row & 7) << 4)));
            *reinterpret_cast<int4*>((char*)orow + c) = v;
        }
    }
}

// ---------------------------------------------------------------------------
// GEMM2: out = ctx @ Wo + bo  (M=4096, N=1024, K=1024), fp32 output.
// ---------------------------------------------------------------------------
__global__ __launch_bounds__(256, 2) void gemm_out_kernel(
    const f16* __restrict__ A, const f16* __restrict__ WT,
    const float* __restrict__ bo, float* __restrict__ out)
{
    __shared__ f16 As[128 * 32];
    __shared__ f16 Bs[128 * 32];
    const int tid = threadIdx.x;
    const int lane = tid & 63;
    const int wid = tid >> 6;
    const int wr = wid >> 1, wc = wid & 1;
    const int lhi = lane >> 4, llo = lane & 15;
    const int row0 = blockIdx.x * 128;
    const int col0 = blockIdx.y * 128;

    f32x4 acc[4][4] = {};

    for (int k0 = 0; k0 < EMBED; k0 += 32) {
        __syncthreads();
#pragma unroll
        for (int i = 0; i < 2; ++i) {
            int li = i * 256 + tid;
            int ar = li >> 2;
            int ac = (li & 3) * 8;
            f16x8 v = *reinterpret_cast<const f16x8*>(
                &A[(size_t)(row0 + ar) * EMBED + k0 + ac]);
            int byte = (ac * 2) ^ ((ar & 3) << 4);
            *reinterpret_cast<f16x8*>((char*)As + ar * 64 + byte) = v;
        }
#pragma unroll
        for (int i = 0; i < 2; ++i) {
            int li = i * 256 + tid;
            int br = li >> 2;
            int bc = (li & 3) * 8;
            f16x8 v = *reinterpret_cast<const f16x8*>(
                &WT[(size_t)(col0 + br) * EMBED + k0 + bc]);
            int byte = (bc * 2) ^ ((br & 3) << 4);
            *reinterpret_cast<f16x8*>((char*)Bs + br * 64 + byte) = v;
        }
        __syncthreads();
        f16x8 af[4], bf[4];
#pragma unroll
        for (int m = 0; m < 4; ++m) {
            int ar = wr * 64 + m * 16 + llo;
            int byte = (lhi * 16) ^ ((ar & 3) << 4);
            af[m] = *reinterpret_cast<const f16x8*>((const char*)As + ar * 64 + byte);
        }
#pragma unroll
        for (int n = 0; n < 4; ++n) {
            int br = wc * 64 + n * 16 + llo;
            int byte = (lhi * 16) ^ ((br & 3) << 4);
            bf[n] = *reinterpret_cast<const f16x8*>((const char*)Bs + br * 64 + byte);
        }
#pragma unroll
        for (int m = 0; m < 4; ++m)
#pragma unroll
            for (int n = 0; n < 4; ++n)
                acc[m][n] = __builtin_amdgcn_mfma_f32_16x16x32_f16(
                    af[m], bf[n], acc[m][n], 0, 0, 0);
    }

#pragma unroll
    for (int m = 0; m < 4; ++m)
#pragma unroll
        for (int n = 0; n < 4; ++n)
#pragma unroll
            for (int r = 0; r < 4; ++r) {
                int mg = row0 + wr * 64 + m * 16 + lhi * 4 + r;
                int ng = col0 + wc * 64 + n * 16 + llo;
                out[(size_t)mg * EMBED + ng] = acc[m][n][r] + bo[ng];
            }
}

// ---------------------------------------------------------------------------
extern "C" void kernel_launch(void* const* d_in, const int* in_sizes, int n_in,
                              void* d_out, int out_size, void* d_ws, size_t ws_size,
                              hipStream_t stream)
{
    const float* x     = (const float*)d_in[0];
    const float* w_qkv = (const float*)d_in[1];
    const float* b_qkv = (const float*)d_in[2];
    const float* w_o   = (const float*)d_in[3];
    const float* b_o   = (const float*)d_in[4];
    float* out = (float*)d_out;

    char* ws = (char*)d_ws;
    f16* wqkvT = (f16*)ws; ws += (size_t)NQKV * EMBED * 2;
    f16* woT   = (f16*)ws; ws += (size_t)EMBED * EMBED * 2;
    f16* Qb    = (f16*)ws; ws += (size_t)BH * SEQ * HDIM * 2;
    f16* Kb    = (f16*)ws; ws += (size_t)BH * SEQ * HDIM * 2;
    f16* Vt    = (f16*)ws; ws += (size_t)BH * SEQ * HDIM * 2;
    f16* ctx   = (f16*)ws; ws += (size_t)MTOK * EMBED * 2;

    hipLaunchKernelGGL(transpose_cvt_kernel, dim3(NQKV / 32, EMBED / 32), dim3(256),
                       0, stream, w_qkv, wqkvT, EMBED, NQKV);
    hipLaunchKernelGGL(transpose_cvt_kernel, dim3(EMBED / 32, EMBED / 32), dim3(256),
                       0, stream, w_o, woT, EMBED, EMBED);
    hipLaunchKernelGGL(gemm_qkv_kernel, dim3(MTOK / 128, NQKV / 128), dim3(256),
                       0, stream, x, wqkvT, b_qkv, Qb, Kb, Vt);
    hipLaunchKernelGGL(attn_kernel, dim3(BH, SEQ / 128), dim3(512),
                       0, stream, Qb, Kb, Vt, ctx);
    hipLaunchKernelGGL(gemm_out_kernel, dim3(MTOK / 128, EMBED / 128), dim3(256),
                       0, stream, ctx, woT, b_o, out);
}

// Round 9
// 130.567 us; speedup vs baseline: 2.2320x; 1.0312x over previous
//
#include <hip/hip_runtime.h>
#include <cstdint>
#include <cstddef>

// Problem constants
#define NHEADS 16
#define HDIM   64
#define EMBED  1024
#define BATCH  2
#define SEQ    2048
#define BH     (BATCH*NHEADS)        // 32
#define MTOK   (BATCH*SEQ)           // 4096
#define NQKV   (3*NHEADS*HDIM)       // 3072

typedef _Float16 f16;
typedef __attribute__((ext_vector_type(2))) _Float16 f16x2;
typedef __attribute__((ext_vector_type(4))) _Float16 f16x4;
typedef __attribute__((ext_vector_type(8))) _Float16 f16x8;
typedef __attribute__((ext_vector_type(4))) float f32x4;
typedef __attribute__((ext_vector_type(16))) float f32x16;

// pack two f32 -> one u32 of 2 f16 (RTZ)
__device__ __forceinline__ unsigned pkf16(float a, float b) {
    return __builtin_bit_cast(unsigned, __builtin_amdgcn_cvt_pkrtz(a, b));
}
// cross-32-lane max/add. shfl_xor-based: HW-proven in rounds 2/5/6/8.
__device__ __forceinline__ float cross32_max(float x) {
    return fmaxf(x, __shfl_xor(x, 32, 64));
}
__device__ __forceinline__ float cross32_add(float x) {
    return x + __shfl_xor(x, 32, 64);
}
// async global->LDS copy, 16B per lane. Dest must be the WAVE-UNIFORM base;
// HW writes lane i at dest + i*16 (guide m97/m104).
__device__ __forceinline__ void gl2lds16(const void* g, void* l) {
    __builtin_amdgcn_global_load_lds(
        (const __attribute__((address_space(1))) unsigned int*)g,
        (__attribute__((address_space(3))) unsigned int*)l, 16, 0, 0);
}

// ---------------------------------------------------------------------------
// fp32 -> f16 elementwise convert (for X)
// ---------------------------------------------------------------------------
__global__ __launch_bounds__(256) void cvt_f32_f16_kernel(
    const float* __restrict__ in, f16* __restrict__ out)
{
    int idx = (blockIdx.x * 256 + threadIdx.x) * 8;
    float4 a = *reinterpret_cast<const float4*>(in + idx);
    float4 b = *reinterpret_cast<const float4*>(in + idx + 4);
    f16x8 h;
    h[0] = (f16)a.x; h[1] = (f16)a.y; h[2] = (f16)a.z; h[3] = (f16)a.w;
    h[4] = (f16)b.x; h[5] = (f16)b.y; h[6] = (f16)b.z; h[7] = (f16)b.w;
    *reinterpret_cast<f16x8*>(out + idx) = h;
}

// ---------------------------------------------------------------------------
// Transpose + fp32->f16 convert:  out[n][k] = (f16) in[k][n]
// ---------------------------------------------------------------------------
__global__ __launch_bounds__(256) void transpose_cvt_kernel(
    const float* __restrict__ in, f16* __restrict__ out, int K, int N)
{
    __shared__ float tile[32][33];
    const int n0 = blockIdx.x * 32;
    const int k0 = blockIdx.y * 32;
    const int tx = threadIdx.x & 31;
    const int ty = threadIdx.x >> 5;
#pragma unroll
    for (int j = 0; j < 4; ++j) {
        int k = ty + j * 8;
        tile[k][tx] = in[(size_t)(k0 + k) * N + n0 + tx];
    }
    __syncthreads();
#pragma unroll
    for (int j = 0; j < 4; ++j) {
        int n = ty + j * 8;
        out[(size_t)(n0 + n) * K + k0 + tx] = (f16)tile[tx][n];
    }
}

// ---------------------------------------------------------------------------
// GEMM1: QKV = Xh @ Wqkv + b  (M=4096, N=3072, K=1024), A/B staged via
// global_load_lds width-16 into LINEAR LDS (m97 structure, 2 barriers/K-step).
// Epilogue: Q row-major (scaled 0.125*log2e), K/V in MFMA-fragment order.
// ---------------------------------------------------------------------------
__global__ __launch_bounds__(256, 2) void gemm_qkv_kernel(
    const f16* __restrict__ Xh, const f16* __restrict__ WT,
    const float* __restrict__ bqkv,
    f16* __restrict__ Qb, f16* __restrict__ Kb, f16* __restrict__ Vt)
{
    __shared__ f16 As[128 * 32];   // linear [row][32], 64B rows
    __shared__ f16 Bs[128 * 32];
    const int tid = threadIdx.x;
    const int lane = tid & 63;
    const int wid = tid >> 6;
    const int wr = wid >> 1, wc = wid & 1;
    const int lhi = lane >> 4, llo = lane & 15;
    const int row0 = blockIdx.x * 128;
    const int col0 = blockIdx.y * 128;

    f32x4 acc[4][4] = {};

    for (int k0 = 0; k0 < EMBED; k0 += 32) {
        __syncthreads();                       // prev frags fully read
#pragma unroll
        for (int i = 0; i < 2; ++i) {
            int li = i * 256 + tid;            // 0..511, 8 elems each
            int r = li >> 2;
            int c = (li & 3) * 8;
            char* dA = (char*)As + i * 4096 + wid * 1024;   // wave-uniform
            char* dB = (char*)Bs + i * 4096 + wid * 1024;
            gl2lds16(Xh + (size_t)(row0 + r) * EMBED + k0 + c, dA);
            gl2lds16(WT + (size_t)(col0 + r) * EMBED + k0 + c, dB);
        }
        __syncthreads();                       // drains vmcnt -> LDS ready
        f16x8 af[4], bf[4];
#pragma unroll
        for (int m = 0; m < 4; ++m)
            af[m] = *reinterpret_cast<const f16x8*>(
                (const char*)As + (wr * 64 + m * 16 + llo) * 64 + lhi * 16);
#pragma unroll
        for (int n = 0; n < 4; ++n)
            bf[n] = *reinterpret_cast<const f16x8*>(
                (const char*)Bs + (wc * 64 + n * 16 + llo) * 64 + lhi * 16);
#pragma unroll
        for (int m = 0; m < 4; ++m)
#pragma unroll
            for (int n = 0; n < 4; ++n)
                acc[m][n] = __builtin_amdgcn_mfma_f32_16x16x32_f16(
                    af[m], bf[n], acc[m][n], 0, 0, 0);
    }

#pragma unroll
    for (int m = 0; m < 4; ++m) {
#pragma unroll
        for (int n = 0; n < 4; ++n) {
#pragma unroll
            for (int r = 0; r < 4; ++r) {
                int mg = row0 + wr * 64 + m * 16 + lhi * 4 + r;
                int ng = col0 + wc * 64 + n * 16 + llo;
                float v = acc[m][n][r] + bqkv[ng];
                int t = ng >> 10;
                int h = (ng >> 6) & 15;
                int d = ng & 63;
                int b = mg >> 11;
                int s = mg & (SEQ - 1);
                int bh = b * NHEADS + h;
                if (t == 0) {
                    Qb[((size_t)bh * SEQ + s) * HDIM + d] = (f16)(v * 0.18033688011f);
                } else if (t == 1) {
                    size_t off = ((size_t)(bh * (SEQ >> 5) + (s >> 5)) * 4 + (d >> 4)) * 512
                               + (size_t)((((d >> 3) & 1) << 5) + (s & 31)) * 8 + (d & 7);
                    Kb[off] = (f16)v;
                } else {
                    size_t off = ((size_t)(bh * (SEQ >> 6) + (s >> 6)) * 8
                                  + (d >> 5) * 4 + ((s >> 4) & 3)) * 512
                               + (size_t)((((s >> 3) & 1) << 5) + (d & 31)) * 8 + (s & 7);
                    Vt[off] = (f16)v;
                }
            }
        }
    }
}

// ---------------------------------------------------------------------------
// Flash attention: swapped-operand in-register softmax, fragment-layout K/V,
// in-block KV-split. Grid (BH, SEQ/128); 8 waves: 0-3 KV[0:1024], 4-7
// KV[1024:2048], same 4 q-tiles. LDS shrunk to 19.5KB (round-8 lesson: 53KB
// blocked 2-blocks/CU residency): Xo partials packed f16-pairs u32[4][64][17]
// (stride 17 = conflict-free), Ol(16KB) unioned into the Xo region with an
// extra barrier between Xo-read and Ol-write. 2 blocks/CU -> 4 waves/SIMD.
// ---------------------------------------------------------------------------
#define LOADK(KF, KB) do {                                                     \
    const f16* kbase_ = Kp + ((size_t)((KB) >> 5) * 4) * 512;                  \
    _Pragma("unroll")                                                          \
    for (int j_ = 0; j_ < 2; ++j_)                                             \
        _Pragma("unroll")                                                      \
        for (int ds_ = 0; ds_ < 4; ++ds_)                                      \
            KF[j_*4+ds_] = *reinterpret_cast<const f16x8*>(                    \
                kbase_ + (size_t)(j_*4 + ds_) * 512 + lane * 8);               \
} while (0)

#define LOADV(VF, KB) do {                                                     \
    const f16* vbase_ = Vp + ((size_t)((KB) >> 6) * 8) * 512;                  \
    _Pragma("unroll")                                                          \
    for (int i_ = 0; i_ < 8; ++i_)                                             \
        VF[i_] = *reinterpret_cast<const f16x8*>(                              \
            vbase_ + (size_t)i_ * 512 + lane * 8);                             \
} while (0)

#define STEP(KF, VF) do {                                                      \
    f32x16 st0 = {}, st1 = {};                                                 \
    __builtin_amdgcn_s_setprio(1);                                             \
    _Pragma("unroll")                                                          \
    for (int ds_ = 0; ds_ < 4; ++ds_) {                                        \
        st0 = __builtin_amdgcn_mfma_f32_32x32x16_f16(KF[ds_],   qf[ds_], st0, 0, 0, 0); \
        st1 = __builtin_amdgcn_mfma_f32_32x32x16_f16(KF[4+ds_], qf[ds_], st1, 0, 0, 0); \
    }                                                                          \
    __builtin_amdgcn_s_setprio(0);                                             \
    float red[16];                                                             \
    _Pragma("unroll")                                                          \
    for (int r_ = 0; r_ < 16; ++r_) red[r_] = fmaxf(st0[r_], st1[r_]);         \
    _Pragma("unroll")                                                          \
    for (int w_ = 8; w_ >= 1; w_ >>= 1)                                        \
        _Pragma("unroll")                                                      \
        for (int r_ = 0; r_ < w_; ++r_) red[r_] = fmaxf(red[r_], red[r_+w_]);  \
    float pm = cross32_max(red[0]);                                            \
    if (!__all(pm - m <= 8.0f)) {                                              \
        float mn = fmaxf(m, pm);                                               \
        float sc = __builtin_amdgcn_exp2f(m - mn);                             \
        m = mn; l *= sc;                                                       \
        _Pragma("unroll")                                                      \
        for (int r_ = 0; r_ < 16; ++r_) { o[0][r_] *= sc; o[1][r_] *= sc; }    \
    }                                                                          \
    _Pragma("unroll")                                                          \
    for (int r_ = 0; r_ < 16; ++r_) {                                          \
        st0[r_] = __builtin_amdgcn_exp2f(st0[r_] - m);                         \
        st1[r_] = __builtin_amdgcn_exp2f(st1[r_] - m);                         \
    }                                                                          \
    _Pragma("unroll")                                                          \
    for (int r_ = 0; r_ < 16; ++r_) red[r_] = st0[r_] + st1[r_];               \
    _Pragma("unroll")                                                          \
    for (int w_ = 8; w_ >= 1; w_ >>= 1)                                        \
        _Pragma("unroll")                                                      \
        for (int r_ = 0; r_ < w_; ++r_) red[r_] += red[r_+w_];                 \
    l += red[0];                                                               \
    f16x8 pf[4];                                                               \
    {                                                                          \
        unsigned a0 = pkf16(st0[0],  st0[1]),  a1 = pkf16(st0[2],  st0[3]);    \
        unsigned b0 = pkf16(st0[4],  st0[5]),  b1 = pkf16(st0[6],  st0[7]);    \
        unsigned c0 = pkf16(st0[8],  st0[9]),  c1 = pkf16(st0[10], st0[11]);   \
        unsigned d0 = pkf16(st0[12], st0[13]), d1 = pkf16(st0[14], st0[15]);   \
        asm("v_permlane32_swap_b32 %0, %1" : "+v"(a0), "+v"(b0));              \
        asm("v_permlane32_swap_b32 %0, %1" : "+v"(a1), "+v"(b1));              \
        asm("v_permlane32_swap_b32 %0, %1" : "+v"(c0), "+v"(d0));              \
        asm("v_permlane32_swap_b32 %0, %1" : "+v"(c1), "+v"(d1));              \
        uint4 w0; w0.x = a0; w0.y = a1; w0.z = b0; w0.w = b1;                  \
        uint4 w1; w1.x = c0; w1.y = c1; w1.z = d0; w1.w = d1;                  \
        pf[0] = __builtin_bit_cast(f16x8, w0);                                 \
        pf[1] = __builtin_bit_cast(f16x8, w1);                                 \
    }                                                                          \
    {                                                                          \
        unsigned a0 = pkf16(st1[0],  st1[1]),  a1 = pkf16(st1[2],  st1[3]);    \
        unsigned b0 = pkf16(st1[4],  st1[5]),  b1 = pkf16(st1[6],  st1[7]);    \
        unsigned c0 = pkf16(st1[8],  st1[9]),  c1 = pkf16(st1[10], st1[11]);   \
        unsigned d0 = pkf16(st1[12], st1[13]), d1 = pkf16(st1[14], st1[15]);   \
        asm("v_permlane32_swap_b32 %0, %1" : "+v"(a0), "+v"(b0));              \
        asm("v_permlane32_swap_b32 %0, %1" : "+v"(a1), "+v"(b1));              \
        asm("v_permlane32_swap_b32 %0, %1" : "+v"(c0), "+v"(d0));              \
        asm("v_permlane32_swap_b32 %0, %1" : "+v"(c1), "+v"(d1));              \
        uint4 w0; w0.x = a0; w0.y = a1; w0.z = b0; w0.w = b1;                  \
        uint4 w1; w1.x = c0; w1.y = c1; w1.z = d0; w1.w = d1;                  \
        pf[2] = __builtin_bit_cast(f16x8, w0);                                 \
        pf[3] = __builtin_bit_cast(f16x8, w1);                                 \
    }                                                                          \
    __builtin_amdgcn_s_setprio(1);                                             \
    _Pragma("unroll")                                                          \
    for (int dt_ = 0; dt_ < 2; ++dt_)                                          \
        _Pragma("unroll")                                                      \
        for (int f_ = 0; f_ < 4; ++f_)                                         \
            o[dt_] = __builtin_amdgcn_mfma_f32_32x32x16_f16(                   \
                VF[dt_*4+f_], pf[f_], o[dt_], 0, 0, 0);                        \
    __builtin_amdgcn_s_setprio(0);                                             \
} while (0)

__global__ __launch_bounds__(512, 2) void attn_kernel(
    const f16* __restrict__ Qb, const f16* __restrict__ Kb,
    const f16* __restrict__ Vt, f16* __restrict__ ctx)
{
    // union region: Xo packed u32[4][64][17] (17408B) overlapped with
    // Ol f16[4][32*64] (16384B); Xml f32[4][64][2] (2048B) after it.
    __shared__ __align__(16) char smem[17408 + 2048];
    unsigned* Xop = (unsigned*)smem;
    float* Xml = (float*)(smem + 17408);
    const int tid = threadIdx.x;
    const int lane = tid & 63;
    const int wid = tid >> 6;         // 0..7
    const int pair = wid & 3;
    const int half = wid >> 2;        // 0: KV[0:1024], 1: KV[1024:2048]
    const int q = lane & 31;
    const int hi = lane >> 5;
    const int bh = blockIdx.x;
    const int q0 = blockIdx.y * 128 + pair * 32;
    const int kb0 = half << 10;
    const f16* Qp = Qb + (size_t)bh * SEQ * HDIM;
    const f16* Kp = Kb + (size_t)bh * SEQ * HDIM;
    const f16* Vp = Vt + (size_t)bh * SEQ * HDIM;

    f16x8 qf[4];
#pragma unroll
    for (int ds = 0; ds < 4; ++ds)
        qf[ds] = *reinterpret_cast<const f16x8*>(
            Qp + (size_t)(q0 + q) * HDIM + ds * 16 + hi * 8);

    f32x16 o[2] = {};
    float m = -1e30f, l = 0.f;

    f16x8 ka[8], kn[8], va[8];
    LOADK(ka, kb0);
    for (int kb = kb0; kb < kb0 + 1024; kb += 128) {
        LOADV(va, kb);
        LOADK(kn, kb + 64);
        STEP(ka, va);
        LOADV(va, kb + 64);
        LOADK(ka, (kb + 128) & (SEQ - 1));
        STEP(kn, va);
    }

    // ---- flash-combine across the two KV halves (per-lane merge)
    if (wid >= 4) {
#pragma unroll
        for (int i = 0; i < 16; ++i) {
            int dt = i >> 3, r = (i & 7) * 2;
            Xop[(pair * 64 + lane) * 17 + i] = pkf16(o[dt][r], o[dt][r + 1]);
        }
        Xml[(pair * 64 + lane) * 2 + 0] = m;
        Xml[(pair * 64 + lane) * 2 + 1] = l;
    }
    __syncthreads();
    if (wid < 4) {
        float mb = Xml[(pair * 64 + lane) * 2 + 0];
        float lb = Xml[(pair * 64 + lane) * 2 + 1];
        float mm = fmaxf(m, mb);
        float sa = __builtin_amdgcn_exp2f(m - mm);
        float sb = __builtin_amdgcn_exp2f(mb - mm);
        l = l * sa + lb * sb;
#pragma unroll
        for (int i = 0; i < 16; ++i) {
            int dt = i >> 3, r = (i & 7) * 2;
            f16x2 p = __builtin_bit_cast(f16x2, Xop[(pair * 64 + lane) * 17 + i]);
            o[dt][r]     = o[dt][r]     * sa + (float)p[0] * sb;
            o[dt][r + 1] = o[dt][r + 1] * sa + (float)p[1] * sb;
        }
    }
    __syncthreads();   // Xo fully read before Ol (aliased) is written
    if (wid < 4) {
        float lt = cross32_add(l);
        float inv = __builtin_amdgcn_rcpf(lt);
        char* base = smem + pair * 4096;
#pragma unroll
        for (int dt = 0; dt < 2; ++dt)
#pragma unroll
            for (int rp = 0; rp < 8; ++rp) {
                int r = rp * 2;
                int d = dt * 32 + (r & 3) + 8 * (r >> 2) + 4 * hi;
                unsigned w = pkf16(o[dt][r] * inv, o[dt][r + 1] * inv);
                int byte = (q * 128 + d * 2) ^ ((q & 7) << 4);
                *reinterpret_cast<unsigned*>(base + byte) = w;
            }
    }
    __syncthreads();
    if (wid < 4) {
        int row = lane >> 1, colh = lane & 1;
        const char* rb = smem + pair * 4096 + row * 128;
        int b = bh >> 4, h = bh & 15;
        f16* orow = ctx + (size_t)(b * SEQ + q0 + row) * EMBED + h * HDIM;
#pragma unroll
        for (int i = 0; i < 4; ++i) {
            int c = colh * 64 + i * 16;
            int4 v = *reinterpret_cast<const int4*>(rb + (c ^ ((row & 7) << 4)));
            *reinterpret_cast<int4*>((char*)orow + c) = v;
        }
    }
}

// ---------------------------------------------------------------------------
// GEMM2: out = ctx @ Wo + bo  (M=4096, N=1024, K=1024), fp32 output.
// global_load_lds staging, linear LDS (m97 structure).
// ---------------------------------------------------------------------------
__global__ __launch_bounds__(256, 2) void gemm_out_kernel(
    const f16* __restrict__ A, const f16* __restrict__ WT,
    const float* __restrict__ bo, float* __restrict__ out)
{
    __shared__ f16 As[128 * 32];
    __shared__ f16 Bs[128 * 32];
    const int tid = threadIdx.x;
    const int lane = tid & 63;
    const int wid = tid >> 6;
    const int wr = wid >> 1, wc = wid & 1;
    const int lhi = lane >> 4, llo = lane & 15;
    const int row0 = blockIdx.x * 128;
    const int col0 = blockIdx.y * 128;

    f32x4 acc[4][4] = {};

    for (int k0 = 0; k0 < EMBED; k0 += 32) {
        __syncthreads();
#pragma unroll
        for (int i = 0; i < 2; ++i) {
            int li = i * 256 + tid;
            int r = li >> 2;
            int c = (li & 3) * 8;
            char* dA = (char*)As + i * 4096 + wid * 1024;
            char* dB = (char*)Bs + i * 4096 + wid * 1024;
            gl2lds16(A  + (size_t)(row0 + r) * EMBED + k0 + c, dA);
            gl2lds16(WT + (size_t)(col0 + r) * EMBED + k0 + c, dB);
        }
        __syncthreads();
        f16x8 af[4], bf[4];
#pragma unroll
        for (int mi = 0; mi < 4; ++mi)
            af[mi] = *reinterpret_cast<const f16x8*>(
                (const char*)As + (wr * 64 + mi * 16 + llo) * 64 + lhi * 16);
#pragma unroll
        for (int n = 0; n < 4; ++n)
            bf[n] = *reinterpret_cast<const f16x8*>(
                (const char*)Bs + (wc * 64 + n * 16 + llo) * 64 + lhi * 16);
#pragma unroll
        for (int mi = 0; mi < 4; ++mi)
#pragma unroll
            for (int n = 0; n < 4; ++n)
                acc[mi][n] = __builtin_amdgcn_mfma_f32_16x16x32_f16(
                    af[mi], bf[n], acc[mi][n], 0, 0, 0);
    }

#pragma unroll
    for (int mi = 0; mi < 4; ++mi)
#pragma unroll
        for (int n = 0; n < 4; ++n)
#pragma unroll
            for (int r = 0; r < 4; ++r) {
                int mg = row0 + wr * 64 + mi * 16 + lhi * 4 + r;
                int ng = col0 + wc * 64 + n * 16 + llo;
                out[(size_t)mg * EMBED + ng] = acc[mi][n][r] + bo[ng];
            }
}

// ---------------------------------------------------------------------------
extern "C" void kernel_launch(void* const* d_in, const int* in_sizes, int n_in,
                              void* d_out, int out_size, void* d_ws, size_t ws_size,
                              hipStream_t stream)
{
    const float* x     = (const float*)d_in[0];
    const float* w_qkv = (const float*)d_in[1];
    const float* b_qkv = (const float*)d_in[2];
    const float* w_o   = (const float*)d_in[3];
    const float* b_o   = (const float*)d_in[4];
    float* out = (float*)d_out;

    char* ws = (char*)d_ws;
    f16* wqkvT = (f16*)ws; ws += (size_t)NQKV * EMBED * 2;       // 6 MB
    f16* woT   = (f16*)ws; ws += (size_t)EMBED * EMBED * 2;      // 2 MB
    f16* Xh    = (f16*)ws; ws += (size_t)MTOK * EMBED * 2;       // 8 MB
    f16* Qb    = (f16*)ws; ws += (size_t)BH * SEQ * HDIM * 2;    // 8 MB
    f16* Kb    = (f16*)ws; ws += (size_t)BH * SEQ * HDIM * 2;    // 8 MB
    f16* Vt    = (f16*)ws; ws += (size_t)BH * SEQ * HDIM * 2;    // 8 MB
    f16* ctx   = (f16*)ws; ws += (size_t)MTOK * EMBED * 2;       // 8 MB (48 MB)

    hipLaunchKernelGGL(cvt_f32_f16_kernel, dim3(MTOK * EMBED / (256 * 8)), dim3(256),
                       0, stream, x, Xh);
    hipLaunchKernelGGL(transpose_cvt_kernel, dim3(NQKV / 32, EMBED / 32), dim3(256),
                       0, stream, w_qkv, wqkvT, EMBED, NQKV);
    hipLaunchKernelGGL(transpose_cvt_kernel, dim3(EMBED / 32, EMBED / 32), dim3(256),
                       0, stream, w_o, woT, EMBED, EMBED);
    hipLaunchKernelGGL(gemm_qkv_kernel, dim3(MTOK / 128, NQKV / 128), dim3(256),
                       0, stream, Xh, wqkvT, b_qkv, Qb, Kb, Vt);
    hipLaunchKernelGGL(attn_kernel, dim3(BH, SEQ / 128), dim3(512),
                       0, stream, Qb, Kb, Vt, ctx);
    hipLaunchKernelGGL(gemm_out_kernel, dim3(MTOK / 128, EMBED / 128), dim3(256),
                       0, stream, ctx, woT, b_o, out);
}